// Round 16
// baseline (370.157 us; speedup 1.0000x reference)
//
#include <hip/hip_runtime.h>
#include <stdint.h>

#define SEQ   2048
#define HID   4096
#define NQH   32
#define NKVH  8
#define HD    128
#define QKVN  6144   // (32 + 2*8) * 128

typedef uint16_t u16;
typedef __attribute__((ext_vector_type(8))) short bf16x8;
typedef __attribute__((ext_vector_type(4))) float f32x4;
typedef __attribute__((ext_vector_type(4))) unsigned int u32x4;

static __device__ __forceinline__ float bf2f(u16 h){
  union { float f; unsigned int u; } v; v.u = ((unsigned int)h) << 16; return v.f;
}
static __device__ __forceinline__ u16 f2bf(float f){
  unsigned int u = __float_as_uint(f);
  return (u16)((u + 0x7fffu + ((u >> 16) & 1u)) >> 16);  // RNE, finite inputs only
}
static __device__ __forceinline__ f32x4 mfma16(bf16x8 a, bf16x8 b, f32x4 c){
  return __builtin_amdgcn_mfma_f32_16x16x32_bf16(a, b, c, 0, 0, 0);
}
static __device__ __forceinline__ void gload16(const void* g, void* l){
  __builtin_amdgcn_global_load_lds((const __attribute__((address_space(1))) void*)g,
                                   (__attribute__((address_space(3))) void*)l, 16, 0, 0);
}

// ---------------- fp32 -> bf16 elementwise (n4 = n/4) ----------------
__global__ void k_cvt(const float* __restrict__ src, u16* __restrict__ dst, int n4){
  int i = blockIdx.x * blockDim.x + threadIdx.x;
  if (i >= n4) return;
  float4 v = ((const float4*)src)[i];
  uint2 o;
  o.x = (unsigned)f2bf(v.x) | ((unsigned)f2bf(v.y) << 16);
  o.y = (unsigned)f2bf(v.z) | ((unsigned)f2bf(v.w) << 16);
  ((uint2*)dst)[i] = o;
}

// ---------------- src[K][N] fp32 -> dst[N][K] bf16 (transpose-convert) ----------------
__global__ void k_transpose_cvt(const float* __restrict__ src, u16* __restrict__ dst, int K, int N){
  __shared__ float t[32][33];
  int n0 = blockIdx.x * 32, k0 = blockIdx.y * 32;
  int tx = threadIdx.x, ty = threadIdx.y;
#pragma unroll
  for (int i = 0; i < 32; i += 8)
    t[ty + i][tx] = src[(size_t)(k0 + ty + i) * N + n0 + tx];
  __syncthreads();
#pragma unroll
  for (int i = 0; i < 32; i += 8)
    dst[(size_t)(n0 + ty + i) * K + k0 + tx] = f2bf(t[tx][ty + i]);
}

// ---------------- GEMM1: C[M][6144] = A @ Bt^T, BN=192 -> 256 blocks (full machine) ----------------
// r12 8-phase structure with BN=192 (measured: ~121 us; FROZEN).
__global__ __launch_bounds__(512) void k_gemm192(const u16* __restrict__ A, const u16* __restrict__ Bt,
                                                 u16* __restrict__ Cv, int M, int N, int K){
  __shared__ __align__(16) u16 Asm[2][256][64];   // 64 KB
  __shared__ __align__(16) u16 Bsm[2][192][64];   // 48 KB
  const int tid = threadIdx.x, lane = tid & 63, wid = tid >> 6;
  const int wm = wid >> 2, wn = wid & 3;
  const int l16 = lane & 15, lhi = lane >> 4;
  const int rx = l16 & 7;
  const int bid = blockIdx.x;
  const int xcd = bid & 7, jj = bid >> 3;
  const size_t bcol = (size_t)(xcd * 4 + jj % 4) * 192;
  const size_t brow = (size_t)((jj / 4) & 7) * 256;

  const f32x4 vz = {0.f, 0.f, 0.f, 0.f};
  f32x4 acc[8][3];
#pragma unroll
  for (int m = 0; m < 8; m++)
#pragma unroll
    for (int n = 0; n < 3; n++) acc[m][n] = vz;

  const int srow = lane >> 3;
  const int sg   = (lane & 7) ^ srow;
  const u16* Ags = A  + (brow + wid*8 + srow) * (size_t)K + sg*8;
  const u16* Bgs = Bt + (bcol + wid*8 + srow) * (size_t)K + sg*8;
  const int NT = K >> 6, NU = NT >> 1;

#define FRA(buf, mi, kh) (*(const bf16x8*)&Asm[buf][wm*128 + (mi)*16 + l16][(((kh)*4 + lhi) ^ rx) << 3])
#define FRB(buf, ni, kh) (*(const bf16x8*)&Bsm[buf][wn*48 + (ni)*16 + l16][(((kh)*4 + lhi) ^ rx) << 3])
#define STG_A(tile, half) do{ if ((tile) < NT){                                  \
    const size_t ko_ = (size_t)((half)*128) * K + (size_t)(tile) * 64;           \
    gload16(Ags + ko_,                &Asm[(tile)&1][(half)*128 + wid*8][0]);     \
    gload16(Ags + ko_ + (size_t)64*K, &Asm[(tile)&1][(half)*128 + 64 + wid*8][0]); } }while(0)
#define STG_B(tile, r) do{ if ((tile) < NT){                                     \
    const size_t ko_ = (size_t)((r)*64) * K + (size_t)(tile) * 64;               \
    gload16(Bgs + ko_, &Bsm[(tile)&1][(r)*64 + wid*8][0]); } }while(0)

  STG_B(0,0); STG_B(0,1); STG_B(0,2);
  STG_A(0,0); STG_A(0,1);
  STG_B(1,0); STG_B(1,1); STG_B(1,2);
  asm volatile("s_waitcnt vmcnt(3)" ::: "memory");
  __builtin_amdgcn_sched_barrier(0);
  __builtin_amdgcn_s_barrier();

  bf16x8 fA[4][2], fB01[2][2], fB2[2];
  for (int u = 0; u < NU; ++u){
    const int t = 2 * u;
    // P0
#pragma unroll
    for (int mi = 0; mi < 4; ++mi){ fA[mi][0] = FRA(0, mi, 0); fA[mi][1] = FRA(0, mi, 1); }
#pragma unroll
    for (int ni = 0; ni < 2; ++ni){ fB01[ni][0] = FRB(0, ni, 0); fB01[ni][1] = FRB(0, ni, 1); }
    STG_A(t + 1, 0);
    asm volatile("s_waitcnt lgkmcnt(8)" ::: "memory");
    __builtin_amdgcn_s_barrier();
    asm volatile("s_waitcnt lgkmcnt(0)" ::: "memory");
    __builtin_amdgcn_sched_barrier(0);
    __builtin_amdgcn_s_setprio(1);
#pragma unroll
    for (int kh = 0; kh < 2; ++kh)
#pragma unroll
      for (int mi = 0; mi < 4; ++mi)
#pragma unroll
        for (int ni = 0; ni < 2; ++ni)
          acc[mi][ni] = mfma16(fA[mi][kh], fB01[ni][kh], acc[mi][ni]);
    __builtin_amdgcn_s_setprio(0);
    __builtin_amdgcn_s_barrier();
    // P1
    fB2[0] = FRB(0, 2, 0); fB2[1] = FRB(0, 2, 1);
    STG_A(t + 1, 1);
    __builtin_amdgcn_s_barrier();
    asm volatile("s_waitcnt lgkmcnt(0)" ::: "memory");
    __builtin_amdgcn_sched_barrier(0);
    __builtin_amdgcn_s_setprio(1);
#pragma unroll
    for (int kh = 0; kh < 2; ++kh)
#pragma unroll
      for (int mi = 0; mi < 4; ++mi)
        acc[mi][2] = mfma16(fA[mi][kh], fB2[kh], acc[mi][2]);
    __builtin_amdgcn_s_setprio(0);
    __builtin_amdgcn_s_barrier();
    // P2
#pragma unroll
    for (int mi = 0; mi < 4; ++mi){ fA[mi][0] = FRA(0, 4 + mi, 0); fA[mi][1] = FRA(0, 4 + mi, 1); }
    STG_B(t + 2, 0);
    __builtin_amdgcn_s_barrier();
    asm volatile("s_waitcnt lgkmcnt(0)" ::: "memory");
    __builtin_amdgcn_sched_barrier(0);
    __builtin_amdgcn_s_setprio(1);
#pragma unroll
    for (int kh = 0; kh < 2; ++kh)
#pragma unroll
      for (int mi = 0; mi < 4; ++mi)
#pragma unroll
        for (int ni = 0; ni < 2; ++ni)
          acc[4 + mi][ni] = mfma16(fA[mi][kh], fB01[ni][kh], acc[4 + mi][ni]);
    __builtin_amdgcn_s_setprio(0);
    __builtin_amdgcn_s_barrier();
    // P3
    STG_B(t + 2, 1); STG_B(t + 2, 2);
    __builtin_amdgcn_s_barrier();
    asm volatile("s_waitcnt lgkmcnt(0)" ::: "memory");
    __builtin_amdgcn_sched_barrier(0);
    __builtin_amdgcn_s_setprio(1);
#pragma unroll
    for (int kh = 0; kh < 2; ++kh)
#pragma unroll
      for (int mi = 0; mi < 4; ++mi)
        acc[4 + mi][2] = mfma16(fA[mi][kh], fB2[kh], acc[4 + mi][2]);
    __builtin_amdgcn_s_setprio(0);
    if (u == NU - 1) asm volatile("s_waitcnt vmcnt(0)" ::: "memory");
    else             asm volatile("s_waitcnt vmcnt(3)" ::: "memory");
    __builtin_amdgcn_sched_barrier(0);
    __builtin_amdgcn_s_barrier();
    // P4
#pragma unroll
    for (int mi = 0; mi < 4; ++mi){ fA[mi][0] = FRA(1, mi, 0); fA[mi][1] = FRA(1, mi, 1); }
#pragma unroll
    for (int ni = 0; ni < 2; ++ni){ fB01[ni][0] = FRB(1, ni, 0); fB01[ni][1] = FRB(1, ni, 1); }
    STG_A(t + 2, 0);
    asm volatile("s_waitcnt lgkmcnt(8)" ::: "memory");
    __builtin_amdgcn_s_barrier();
    asm volatile("s_waitcnt lgkmcnt(0)" ::: "memory");
    __builtin_amdgcn_sched_barrier(0);
    __builtin_amdgcn_s_setprio(1);
#pragma unroll
    for (int kh = 0; kh < 2; ++kh)
#pragma unroll
      for (int mi = 0; mi < 4; ++mi)
#pragma unroll
        for (int ni = 0; ni < 2; ++ni)
          acc[mi][ni] = mfma16(fA[mi][kh], fB01[ni][kh], acc[mi][ni]);
    __builtin_amdgcn_s_setprio(0);
    __builtin_amdgcn_s_barrier();
    // P5
    fB2[0] = FRB(1, 2, 0); fB2[1] = FRB(1, 2, 1);
    STG_A(t + 2, 1);
    __builtin_amdgcn_s_barrier();
    asm volatile("s_waitcnt lgkmcnt(0)" ::: "memory");
    __builtin_amdgcn_sched_barrier(0);
    __builtin_amdgcn_s_setprio(1);
#pragma unroll
    for (int kh = 0; kh < 2; ++kh)
#pragma unroll
      for (int mi = 0; mi < 4; ++mi)
        acc[mi][2] = mfma16(fA[mi][kh], fB2[kh], acc[mi][2]);
    __builtin_amdgcn_s_setprio(0);
    __builtin_amdgcn_s_barrier();
    // P6
#pragma unroll
    for (int mi = 0; mi < 4; ++mi){ fA[mi][0] = FRA(1, 4 + mi, 0); fA[mi][1] = FRA(1, 4 + mi, 1); }
    STG_B(t + 3, 0);
    __builtin_amdgcn_s_barrier();
    asm volatile("s_waitcnt lgkmcnt(0)" ::: "memory");
    __builtin_amdgcn_sched_barrier(0);
    __builtin_amdgcn_s_setprio(1);
#pragma unroll
    for (int kh = 0; kh < 2; ++kh)
#pragma unroll
      for (int mi = 0; mi < 4; ++mi)
#pragma unroll
        for (int ni = 0; ni < 2; ++ni)
          acc[4 + mi][ni] = mfma16(fA[mi][kh], fB01[ni][kh], acc[4 + mi][ni]);
    __builtin_amdgcn_s_setprio(0);
    __builtin_amdgcn_s_barrier();
    // P7
    STG_B(t + 3, 1); STG_B(t + 3, 2);
    __builtin_amdgcn_s_barrier();
    asm volatile("s_waitcnt lgkmcnt(0)" ::: "memory");
    __builtin_amdgcn_sched_barrier(0);
    __builtin_amdgcn_s_setprio(1);
#pragma unroll
    for (int kh = 0; kh < 2; ++kh)
#pragma unroll
      for (int mi = 0; mi < 4; ++mi)
        acc[4 + mi][2] = mfma16(fA[mi][kh], fB2[kh], acc[4 + mi][2]);
    __builtin_amdgcn_s_setprio(0);
    asm volatile("s_waitcnt vmcnt(3)" ::: "memory");
    __builtin_amdgcn_sched_barrier(0);
    __builtin_amdgcn_s_barrier();
  }
#undef FRA
#undef FRB
#undef STG_A
#undef STG_B

#pragma unroll
  for (int mi = 0; mi < 8; mi++)
#pragma unroll
    for (int ni = 0; ni < 3; ni++)
#pragma unroll
      for (int i = 0; i < 4; i++){
        size_t row = brow + wm*128 + mi*16 + lhi*4 + i;
        size_t col = bcol + wn*48 + ni*16 + l16;
        Cv[row * (size_t)N + col] = f2bf(acc[mi][ni][i]);
      }
}

// ---------------- GEMM2: 128x128 tile, 64 KB LDS, 2 blocks/CU, fp32 out (FROZEN) ----------------
__global__ __launch_bounds__(256) void k_gemm128(const u16* __restrict__ A, const u16* __restrict__ Bt,
                                                 float* __restrict__ Cv, int M, int N, int K){
  __shared__ __align__(16) u16 Asm[2][128][64];   // 32 KB
  __shared__ __align__(16) u16 Bsm[2][128][64];   // 32 KB
  const int tid = threadIdx.x, lane = tid & 63, wid = tid >> 6;   // 4 waves
  const int wm = wid >> 1, wn = wid & 1;
  const int l16 = lane & 15, lhi = lane >> 4;
  const int rx = l16 & 7;
  const int bid = blockIdx.x;
  const int xcd = bid & 7, jj = bid >> 3;          // 64 per XCD
  const size_t bcol = (size_t)(xcd * 4 + (jj & 3)) * 128;   // 32 bcols
  const size_t brow = (size_t)(jj >> 2) * 128;              // 16 brows

  const f32x4 vz = {0.f, 0.f, 0.f, 0.f};
  f32x4 acc[4][4];
#pragma unroll
  for (int m = 0; m < 4; m++)
#pragma unroll
    for (int n = 0; n < 4; n++) acc[m][n] = vz;

  const int srow = lane >> 3;                       // 0..7
  const int sg   = (lane & 7) ^ srow;               // pre-swizzled source granule
  const u16* Ags = A  + (brow + wid*8 + srow) * (size_t)K + sg*8;
  const u16* Bgs = Bt + (bcol + wid*8 + srow) * (size_t)K + sg*8;
  const int NT = K >> 6;

#define FRA2(buf, mi, kh) (*(const bf16x8*)&Asm[buf][wm*64 + (mi)*16 + l16][(((kh)*4 + lhi) ^ rx) << 3])
#define FRB2(buf, ni, kh) (*(const bf16x8*)&Bsm[buf][wn*64 + (ni)*16 + l16][(((kh)*4 + lhi) ^ rx) << 3])
#define STG2(tile) do{ if ((tile) < NT){                                          \
    const size_t ko_ = (size_t)(tile) * 64;                                       \
    _Pragma("unroll")                                                             \
    for (int r_ = 0; r_ < 4; ++r_){                                               \
      gload16(Ags + (size_t)(r_*32)*K + ko_, &Asm[(tile)&1][r_*32 + wid*8][0]);   \
      gload16(Bgs + (size_t)(r_*32)*K + ko_, &Bsm[(tile)&1][r_*32 + wid*8][0]);   \
    } } }while(0)

  STG2(0);
  asm volatile("s_waitcnt vmcnt(0)" ::: "memory");
  __builtin_amdgcn_sched_barrier(0);
  __builtin_amdgcn_s_barrier();

  bf16x8 fa[4], fb[4];
  for (int t = 0; t < NT; ++t){
    const int cur = t & 1;
    STG2(t + 1);
#pragma unroll
    for (int mi = 0; mi < 4; ++mi) fa[mi] = FRA2(cur, mi, 0);
#pragma unroll
    for (int ni = 0; ni < 4; ++ni) fb[ni] = FRB2(cur, ni, 0);
    __builtin_amdgcn_s_barrier();
    asm volatile("s_waitcnt lgkmcnt(0)" ::: "memory");
    __builtin_amdgcn_sched_barrier(0);
    __builtin_amdgcn_s_setprio(1);
#pragma unroll
    for (int mi = 0; mi < 4; ++mi)
#pragma unroll
      for (int ni = 0; ni < 4; ++ni)
        acc[mi][ni] = mfma16(fa[mi], fb[ni], acc[mi][ni]);
    __builtin_amdgcn_s_setprio(0);
    __builtin_amdgcn_s_barrier();
#pragma unroll
    for (int mi = 0; mi < 4; ++mi) fa[mi] = FRA2(cur, mi, 1);
#pragma unroll
    for (int ni = 0; ni < 4; ++ni) fb[ni] = FRB2(cur, ni, 1);
    __builtin_amdgcn_s_barrier();
    asm volatile("s_waitcnt lgkmcnt(0)" ::: "memory");
    __builtin_amdgcn_sched_barrier(0);
    __builtin_amdgcn_s_setprio(1);
#pragma unroll
    for (int mi = 0; mi < 4; ++mi)
#pragma unroll
      for (int ni = 0; ni < 4; ++ni)
        acc[mi][ni] = mfma16(fa[mi], fb[ni], acc[mi][ni]);
    __builtin_amdgcn_s_setprio(0);
    asm volatile("s_waitcnt vmcnt(0)" ::: "memory");
    __builtin_amdgcn_sched_barrier(0);
    __builtin_amdgcn_s_barrier();
  }
#undef FRA2
#undef FRB2
#undef STG2

#pragma unroll
  for (int mi = 0; mi < 4; mi++)
#pragma unroll
    for (int ni = 0; ni < 4; ni++)
#pragma unroll
      for (int i = 0; i < 4; i++){
        size_t row = brow + wm*64 + mi*16 + lhi*4 + i;
        size_t col = bcol + wn*64 + ni*16 + l16;
        Cv[row * (size_t)N + col] = acc[mi][ni][i];
      }
}

// ---------------- RMSNorm + RoPE ----------------
__global__ __launch_bounds__(256) void k_rmsrope(const u16* __restrict__ qkv, const float* __restrict__ cosp,
                                                 const float* __restrict__ sinp, const float* __restrict__ qw,
                                                 const float* __restrict__ kw, u16* __restrict__ Qr,
                                                 u16* __restrict__ Kr){
  int t = blockIdx.x;
  int lane = threadIdx.x & 63, w = threadIdx.x >> 6;
  int hh = blockIdx.y * 4 + w;
  bool isq = hh < NQH;
  int hl = isq ? hh : hh - NQH;
  const u16* src = qkv + (size_t)t * QKVN + (isq ? hl * HD : NQH * HD + hl * HD);
  unsigned u = *(const unsigned*)(src + 2 * lane);
  float x0 = bf2f((u16)(u & 0xffffu)), x1 = bf2f((u16)(u >> 16));
  float ss = x0 * x0 + x1 * x1;
#pragma unroll
  for (int m = 1; m < 64; m <<= 1) ss += __shfl_xor(ss, m);
  float rs = rsqrtf(ss * (1.f / HD) + 1e-6f);
  const float* wp = isq ? qw : kw;
  float w0 = wp[2 * lane], w1 = wp[2 * lane + 1];
  float xn0 = x0 * rs * w0, xn1 = x1 * rs * w1;
  float p0 = __shfl_xor(xn0, 32), p1 = __shfl_xor(xn1, 32);
  int j0 = (2 * lane) & 63;
  float c0 = cosp[t * 64 + j0], c1 = cosp[t * 64 + j0 + 1];
  float s0 = sinp[t * 64 + j0], s1 = sinp[t * 64 + j0 + 1];
  float o0, o1;
  if (lane < 32){ o0 = xn0 * c0 - p0 * s0; o1 = xn1 * c1 - p1 * s1; }
  else          { o0 = xn0 * c0 + p0 * s0; o1 = xn1 * c1 + p1 * s1; }
  if (isq){ o0 *= 0.08838834764831845f; o1 *= 0.08838834764831845f; }
  u16* dst = isq ? (Qr + ((size_t)hl * SEQ + t) * HD) : (Kr + ((size_t)hl * SEQ + t) * HD);
  *(unsigned*)(dst + 2 * lane) = (unsigned)f2bf(o0) | ((unsigned)f2bf(o1) << 16);
}

// ---------------- V slice -> VT[h][d][t] ----------------
__global__ void k_vt(const u16* __restrict__ qkv, u16* __restrict__ VT){
  __shared__ u16 t[32][33];
  int t0 = blockIdx.x * 32, d0 = blockIdx.y * 32, hv = blockIdx.z;
  int tx = threadIdx.x, ty = threadIdx.y;
#pragma unroll
  for (int i = 0; i < 32; i += 8)
    t[ty + i][tx] = qkv[(size_t)(t0 + ty + i) * QKVN + (NQH + NKVH) * HD + hv * HD + d0 + tx];
  __syncthreads();
#pragma unroll
  for (int i = 0; i < 32; i += 8)
    VT[((size_t)hv * HD + d0 + ty + i) * SEQ + t0 + tx] = t[tx][ty + i];
}

// ---------------- causal GQA flash attention: balanced-pair q-tiles on r11 machinery ----------------
// 256 blocks = exactly 1/CU, zero imbalance: block owns q-tiles A=(J)*128 and B=(15-J)*128,
// sharing ONE K/V stage stream (kv 0..(15-J)*128+127). Every block = exactly 17
// tile-computations (vs 24-trip makespan of the 2-round longest-first grid).
// Per trip: stage V(t)+K(t+1) -> QK/softmax B (always) + A (while t<=J_A, wave-uniform)
// -> P_B -> vmcnt(4)+barrier -> PV_B -> sched_barrier -> P_A -> PV_A (same-wave in-order
// DS, r13-validated) -> vmcnt(0)+barrier. All r11 swizzles/waits unchanged.
__global__ __launch_bounds__(512) void k_attn(const u16* __restrict__ Q, const u16* __restrict__ Kg,
                                              const u16* __restrict__ VTg, u16* __restrict__ AO){
  __shared__ __align__(16) u16 Ksm[2][128][128];  // 64 KB, granule-swizzled (key row&7)
  __shared__ __align__(16) u16 Vsm[128][128];     // 32 KB [d][kv], swizzled (key d&7)
  __shared__ __align__(16) u16 Psm[8][16][136];   // 34.8 KB per-wave P [q][kv]
  int tid = threadIdx.x, lane = tid & 63, wid = tid >> 6;
  int l16 = lane & 15, lhi = lane >> 4;
  int bid = blockIdx.x;
  int kvg = bid & 7, rr = bid >> 3;               // 32 blocks per kv-group
  int JA = rr >> 2;                               // 0..7
  int JB = 15 - JA;                               // 8..15
  int hq = kvg * 4 + (rr & 3);
  int qbA = JA * 128, qbB = JB * 128;
  const u16* Kh = Kg  + (size_t)kvg * SEQ * HD;
  const u16* Vh = VTg + (size_t)kvg * HD * SEQ;
  const u16* Qh = Q   + (size_t)hq * SEQ * HD;

  bf16x8 qfA[4], qfB[4];
#pragma unroll
  for (int ks = 0; ks < 4; ks++){
    qfA[ks] = *(const bf16x8*)(Qh + (size_t)(qbA + wid*16 + l16) * HD + ks*32 + lhi*8);
    qfB[ks] = *(const bf16x8*)(Qh + (size_t)(qbB + wid*16 + l16) * HD + ks*32 + lhi*8);
  }

  const f32x4 vz = {0.f, 0.f, 0.f, 0.f};
  f32x4 oA[8], oB[8];
  float mA[4], lA[4], mB[4], lB[4];
#pragma unroll
  for (int n = 0; n < 8; n++){ oA[n] = vz; oB[n] = vz; }
#pragma unroll
  for (int i = 0; i < 4; i++){ mA[i] = -1e30f; lA[i] = 0.f; mB[i] = -1e30f; lB[i] = 0.f; }

  int rsub = lane >> 4, g = lane & 15;
  const u16 *Ks0, *Ks1, *Ks2, *Ks3, *Vs0, *Vs1, *Vs2, *Vs3;
  {
    int r0 = wid*16 + 0*4 + rsub, r1 = wid*16 + 1*4 + rsub;
    int r2 = wid*16 + 2*4 + rsub, r3 = wid*16 + 3*4 + rsub;
    Ks0 = Kh + (size_t)r0 * HD + ((g ^ (r0 & 7)) << 3);
    Ks1 = Kh + (size_t)r1 * HD + ((g ^ (r1 & 7)) << 3);
    Ks2 = Kh + (size_t)r2 * HD + ((g ^ (r2 & 7)) << 3);
    Ks3 = Kh + (size_t)r3 * HD + ((g ^ (r3 & 7)) << 3);
    Vs0 = Vh + (size_t)r0 * SEQ + ((g ^ (r0 & 7)) << 3);
    Vs1 = Vh + (size_t)r1 * SEQ + ((g ^ (r1 & 7)) << 3);
    Vs2 = Vh + (size_t)r2 * SEQ + ((g ^ (r2 & 7)) << 3);
    Vs3 = Vh + (size_t)r3 * SEQ + ((g ^ (r3 & 7)) << 3);
  }

  gload16(Ks0, &Ksm[0][wid*16 +  0][0]);
  gload16(Ks1, &Ksm[0][wid*16 +  4][0]);
  gload16(Ks2, &Ksm[0][wid*16 +  8][0]);
  gload16(Ks3, &Ksm[0][wid*16 + 12][0]);
  asm volatile("s_waitcnt vmcnt(0)" ::: "memory");
  __builtin_amdgcn_sched_barrier(0);
  __builtin_amdgcn_s_barrier();

  int ntr = JB + 1;
  int wrA = qbA + wid*16, wrB = qbB + wid*16;
  for (int t = 0; t < ntr; t++){
    int cur = t & 1, nxt = cur ^ 1;
    int kt0 = t << 7;
    bool pf = (t + 1 < ntr);
    bool actA = (t <= JA);               // wave-uniform
    gload16(Vs0 + kt0, &Vsm[wid*16 +  0][0]);
    gload16(Vs1 + kt0, &Vsm[wid*16 +  4][0]);
    gload16(Vs2 + kt0, &Vsm[wid*16 +  8][0]);
    gload16(Vs3 + kt0, &Vsm[wid*16 + 12][0]);
    if (pf){
      size_t ko = (size_t)(kt0 + 128) * HD;
      gload16(Ks0 + ko, &Ksm[nxt][wid*16 +  0][0]);
      gload16(Ks1 + ko, &Ksm[nxt][wid*16 +  4][0]);
      gload16(Ks2 + ko, &Ksm[nxt][wid*16 +  8][0]);
      gload16(Ks3 + ko, &Ksm[nxt][wid*16 + 12][0]);
    }
    const u16* kbase = &Ksm[cur][0][0];
    // ---- QK + softmax, tile B (always) ----
    f32x4 sB[8];
#pragma unroll
    for (int n = 0; n < 8; n++) sB[n] = vz;
    __builtin_amdgcn_s_setprio(1);
#pragma unroll
    for (int n = 0; n < 8; n++){
      int row = n*16 + l16, rxk = row & 7;
#pragma unroll
      for (int ks = 0; ks < 4; ks++){
        bf16x8 kf = *(const bf16x8*)(kbase + row*128 + (((ks*4 + lhi) ^ rxk) << 3));
        sB[n] = mfma16(qfB[ks], kf, sB[n]);
      }
    }
    __builtin_amdgcn_s_setprio(0);
    if (kt0 + 127 > wrB){
#pragma unroll
      for (int n = 0; n < 8; n++)
#pragma unroll
        for (int i = 0; i < 4; i++)
          if (kt0 + n*16 + l16 > wrB + lhi*4 + i) sB[n][i] = -1e30f;
    }
#pragma unroll
    for (int i = 0; i < 4; i++){
      float tm = fmaxf(fmaxf(fmaxf(sB[0][i], sB[1][i]), fmaxf(sB[2][i], sB[3][i])),
                       fmaxf(fmaxf(sB[4][i], sB[5][i]), fmaxf(sB[6][i], sB[7][i])));
      tm = fmaxf(tm, __shfl_xor(tm, 1));
      tm = fmaxf(tm, __shfl_xor(tm, 2));
      tm = fmaxf(tm, __shfl_xor(tm, 4));
      tm = fmaxf(tm, __shfl_xor(tm, 8));
      float nm = fmaxf(mB[i], tm);
      float sc = __expf(mB[i] - nm);
      mB[i] = nm;
      float rsum = 0.f;
#pragma unroll
      for (int n = 0; n < 8; n++){
        float p = __expf(sB[n][i] - nm);
        sB[n][i] = p;
        rsum += p;
      }
      rsum += __shfl_xor(rsum, 1);
      rsum += __shfl_xor(rsum, 2);
      rsum += __shfl_xor(rsum, 4);
      rsum += __shfl_xor(rsum, 8);
      lB[i] = lB[i] * sc + rsum;
#pragma unroll
      for (int n = 0; n < 8; n++) oB[n][i] *= sc;
    }
    // ---- QK + softmax, tile A (while active) ----
    f32x4 sA[8];
    if (actA){
#pragma unroll
      for (int n = 0; n < 8; n++) sA[n] = vz;
      __builtin_amdgcn_s_setprio(1);
#pragma unroll
      for (int n = 0; n < 8; n++){
        int row = n*16 + l16, rxk = row & 7;
#pragma unroll
        for (int ks = 0; ks < 4; ks++){
          bf16x8 kf = *(const bf16x8*)(kbase + row*128 + (((ks*4 + lhi) ^ rxk) << 3));
          sA[n] = mfma16(qfA[ks], kf, sA[n]);
        }
      }
      __builtin_amdgcn_s_setprio(0);
      if (kt0 + 127 > wrA){
#pragma unroll
        for (int n = 0; n < 8; n++)
#pragma unroll
          for (int i = 0; i < 4; i++)
            if (kt0 + n*16 + l16 > wrA + lhi*4 + i) sA[n][i] = -1e30f;
      }
#pragma unroll
      for (int i = 0; i < 4; i++){
        float tm = fmaxf(fmaxf(fmaxf(sA[0][i], sA[1][i]), fmaxf(sA[2][i], sA[3][i])),
                         fmaxf(fmaxf(sA[4][i], sA[5][i]), fmaxf(sA[6][i], sA[7][i])));
        tm = fmaxf(tm, __shfl_xor(tm, 1));
        tm = fmaxf(tm, __shfl_xor(tm, 2));
        tm = fmaxf(tm, __shfl_xor(tm, 4));
        tm = fmaxf(tm, __shfl_xor(tm, 8));
        float nm = fmaxf(mA[i], tm);
        float sc = __expf(mA[i] - nm);
        mA[i] = nm;
        float rsum = 0.f;
#pragma unroll
        for (int n = 0; n < 8; n++){
          float p = __expf(sA[n][i] - nm);
          sA[n][i] = p;
          rsum += p;
        }
        rsum += __shfl_xor(rsum, 1);
        rsum += __shfl_xor(rsum, 2);
        rsum += __shfl_xor(rsum, 4);
        rsum += __shfl_xor(rsum, 8);
        lA[i] = lA[i] * sc + rsum;
#pragma unroll
        for (int n = 0; n < 8; n++) oA[n][i] *= sc;
      }
    }
    // ---- P_B -> LDS; V barrier; PV_B; then P_A -> LDS; PV_A (same-wave in-order DS) ----
#pragma unroll
    for (int n = 0; n < 8; n++)
#pragma unroll
      for (int i = 0; i < 4; i++)
        Psm[wid][lhi*4 + i][n*16 + l16] = f2bf(sB[n][i]);
    if (pf) asm volatile("s_waitcnt vmcnt(4)" ::: "memory");
    else    asm volatile("s_waitcnt vmcnt(0)" ::: "memory");
    __builtin_amdgcn_sched_barrier(0);
    __builtin_amdgcn_s_barrier();
    __builtin_amdgcn_sched_barrier(0);
    __builtin_amdgcn_s_setprio(1);
#pragma unroll
    for (int ksv = 0; ksv < 4; ksv++){
      bf16x8 pa = *(const bf16x8*)&Psm[wid][l16][ksv*32 + lhi*8];
#pragma unroll
      for (int n = 0; n < 8; n++){
        int row = n*16 + l16;
        bf16x8 vb = *(const bf16x8*)(&Vsm[0][0] + row*128 + (((ksv*4 + lhi) ^ (row & 7)) << 3));
        oB[n] = mfma16(pa, vb, oB[n]);
      }
    }
    __builtin_amdgcn_s_setprio(0);
    if (actA){
      __builtin_amdgcn_sched_barrier(0);   // pin pa_B reads before P_A overwrites
#pragma unroll
      for (int n = 0; n < 8; n++)
#pragma unroll
        for (int i = 0; i < 4; i++)
          Psm[wid][lhi*4 + i][n*16 + l16] = f2bf(sA[n][i]);
      __builtin_amdgcn_s_setprio(1);
#pragma unroll
      for (int ksv = 0; ksv < 4; ksv++){
        bf16x8 pa = *(const bf16x8*)&Psm[wid][l16][ksv*32 + lhi*8];
#pragma unroll
        for (int n = 0; n < 8; n++){
          int row = n*16 + l16;
          bf16x8 vb = *(const bf16x8*)(&Vsm[0][0] + row*128 + (((ksv*4 + lhi) ^ (row & 7)) << 3));
          oA[n] = mfma16(pa, vb, oA[n]);
        }
      }
      __builtin_amdgcn_s_setprio(0);
    }
    asm volatile("s_waitcnt vmcnt(0)" ::: "memory");
    __builtin_amdgcn_sched_barrier(0);
    __builtin_amdgcn_s_barrier();
  }
  // epilogue: both tiles
  float invA[4], invB[4];
#pragma unroll
  for (int i = 0; i < 4; i++){ invA[i] = 1.f / lA[i]; invB[i] = 1.f / lB[i]; }
#pragma unroll
  for (int n = 0; n < 8; n++)
#pragma unroll
    for (int i = 0; i < 4; i++){
      int trA = wrA + lhi*4 + i, trB = wrB + lhi*4 + i;
      AO[(size_t)trA * HID + hq * HD + n*16 + l16] = f2bf(oA[n][i] * invA[i]);
      AO[(size_t)trB * HID + hq * HD + n*16 + l16] = f2bf(oB[n][i] * invB[i]);
    }
}

// ---------------- launch ----------------
extern "C" void kernel_launch(void* const* d_in, const int* in_sizes, int n_in,
                              void* d_out, int out_size, void* d_ws, size_t ws_size,
                              hipStream_t stream){
  const float* hs   = (const float*)d_in[0];
  const float* cosp = (const float*)d_in[1];
  const float* sinp = (const float*)d_in[2];
  const float* wqkv = (const float*)d_in[3];
  const float* wo   = (const float*)d_in[4];
  const float* qw   = (const float*)d_in[5];
  const float* kw   = (const float*)d_in[6];
  float* out = (float*)d_out;
  char* ws = (char*)d_ws;
  u16* XB    = (u16*)(ws + 0);            // 16.8 MB  X bf16 [2048][4096]
  u16* WQKVT = (u16*)(ws + 16777216);     // 50.3 MB  WqkvT bf16 [6144][4096]
  u16* WOT   = (u16*)(ws + 0);            // 33.6 MB  WoT bf16 [4096][4096] (after GEMM1)
  u16* QKV   = (u16*)(ws + 67108864);     // 25.2 MB  qkv bf16 [2048][6144]
  u16* QR    = (u16*)(ws + 92274688);     // 16.8 MB  Q bf16 [32][2048][128]
  u16* KR    = (u16*)(ws + 109051904);    //  4.2 MB  K bf16 [8][2048][128]
  u16* VTB   = (u16*)(ws + 113246208);    //  4.2 MB  VT bf16 [8][128][2048]
  u16* AOB   = (u16*)(ws + 117440512);    // 16.8 MB  attn out bf16 [2048][4096]

  k_cvt<<<(SEQ * HID / 4 + 255) / 256, 256, 0, stream>>>(hs, XB, SEQ * HID / 4);
  k_transpose_cvt<<<dim3(QKVN / 32, HID / 32), dim3(32, 8), 0, stream>>>(wqkv, WQKVT, HID, QKVN);
  // GEMM1: BN=192 -> 256 blocks = 8 XCD x (4 bcol x 8 brow), full machine
  k_gemm192<<<256, 512, 0, stream>>>(XB, WQKVT, QKV, SEQ, QKVN, HID);
  k_transpose_cvt<<<dim3(HID / 32, HID / 32), dim3(32, 8), 0, stream>>>(wo, WOT, HID, HID);
  k_rmsrope<<<dim3(SEQ, 10), 256, 0, stream>>>(QKV, cosp, sinp, qw, kw, QR, KR);
  k_vt<<<dim3(SEQ / 32, HD / 32, NKVH), dim3(32, 8), 0, stream>>>(QKV, VTB);
  // attn: balanced-pair q-tiles, 256 blocks = exactly 1/CU
  k_attn<<<256, 512, 0, stream>>>(QR, KR, VTB, AOB);
  // GEMM2: 128^2 tile, 512 blocks = 2 blocks/CU, fp32 out direct
  k_gemm128<<<512, 256, 0, stream>>>(AOB, WOT, out, SEQ, HID, HID);
}

// Round 17
// 330.729 us; speedup vs baseline: 1.1192x; 1.1192x over previous
//
#include <hip/hip_runtime.h>
#include <stdint.h>

#define SEQ   2048
#define HID   4096
#define NQH   32
#define NKVH  8
#define HD    128
#define QKVN  6144   // (32 + 2*8) * 128

typedef uint16_t u16;
typedef __attribute__((ext_vector_type(8))) short bf16x8;
typedef __attribute__((ext_vector_type(4))) float f32x4;
typedef __attribute__((ext_vector_type(4))) unsigned int u32x4;

static __device__ __forceinline__ float bf2f(u16 h){
  union { float f; unsigned int u; } v; v.u = ((unsigned int)h) << 16; return v.f;
}
static __device__ __forceinline__ u16 f2bf(float f){
  unsigned int u = __float_as_uint(f);
  return (u16)((u + 0x7fffu + ((u >> 16) & 1u)) >> 16);  // RNE, finite inputs only
}
static __device__ __forceinline__ f32x4 mfma16(bf16x8 a, bf16x8 b, f32x4 c){
  return __builtin_amdgcn_mfma_f32_16x16x32_bf16(a, b, c, 0, 0, 0);
}
static __device__ __forceinline__ void gload16(const void* g, void* l){
  __builtin_amdgcn_global_load_lds((const __attribute__((address_space(1))) void*)g,
                                   (__attribute__((address_space(3))) void*)l, 16, 0, 0);
}

// ---------------- fp32 -> bf16 elementwise (n4 = n/4) ----------------
__global__ void k_cvt(const float* __restrict__ src, u16* __restrict__ dst, int n4){
  int i = blockIdx.x * blockDim.x + threadIdx.x;
  if (i >= n4) return;
  float4 v = ((const float4*)src)[i];
  uint2 o;
  o.x = (unsigned)f2bf(v.x) | ((unsigned)f2bf(v.y) << 16);
  o.y = (unsigned)f2bf(v.z) | ((unsigned)f2bf(v.w) << 16);
  ((uint2*)dst)[i] = o;
}

// ---------------- src[K][N] fp32 -> dst[N][K] bf16 (transpose-convert) ----------------
__global__ void k_transpose_cvt(const float* __restrict__ src, u16* __restrict__ dst, int K, int N){
  __shared__ float t[32][33];
  int n0 = blockIdx.x * 32, k0 = blockIdx.y * 32;
  int tx = threadIdx.x, ty = threadIdx.y;
#pragma unroll
  for (int i = 0; i < 32; i += 8)
    t[ty + i][tx] = src[(size_t)(k0 + ty + i) * N + n0 + tx];
  __syncthreads();
#pragma unroll
  for (int i = 0; i < 32; i += 8)
    dst[(size_t)(n0 + ty + i) * K + k0 + tx] = f2bf(t[tx][ty + i]);
}

// ---------------- GEMM1: C[M][6144] = A @ Bt^T, BN=192 -> 256 blocks (full machine) ----------------
// r12 8-phase structure with BN=192 (measured: ~121 us; FROZEN).
__global__ __launch_bounds__(512) void k_gemm192(const u16* __restrict__ A, const u16* __restrict__ Bt,
                                                 u16* __restrict__ Cv, int M, int N, int K){
  __shared__ __align__(16) u16 Asm[2][256][64];   // 64 KB
  __shared__ __align__(16) u16 Bsm[2][192][64];   // 48 KB
  const int tid = threadIdx.x, lane = tid & 63, wid = tid >> 6;
  const int wm = wid >> 2, wn = wid & 3;
  const int l16 = lane & 15, lhi = lane >> 4;
  const int rx = l16 & 7;
  const int bid = blockIdx.x;
  const int xcd = bid & 7, jj = bid >> 3;
  const size_t bcol = (size_t)(xcd * 4 + jj % 4) * 192;
  const size_t brow = (size_t)((jj / 4) & 7) * 256;

  const f32x4 vz = {0.f, 0.f, 0.f, 0.f};
  f32x4 acc[8][3];
#pragma unroll
  for (int m = 0; m < 8; m++)
#pragma unroll
    for (int n = 0; n < 3; n++) acc[m][n] = vz;

  const int srow = lane >> 3;
  const int sg   = (lane & 7) ^ srow;
  const u16* Ags = A  + (brow + wid*8 + srow) * (size_t)K + sg*8;
  const u16* Bgs = Bt + (bcol + wid*8 + srow) * (size_t)K + sg*8;
  const int NT = K >> 6, NU = NT >> 1;

#define FRA(buf, mi, kh) (*(const bf16x8*)&Asm[buf][wm*128 + (mi)*16 + l16][(((kh)*4 + lhi) ^ rx) << 3])
#define FRB(buf, ni, kh) (*(const bf16x8*)&Bsm[buf][wn*48 + (ni)*16 + l16][(((kh)*4 + lhi) ^ rx) << 3])
#define STG_A(tile, half) do{ if ((tile) < NT){                                  \
    const size_t ko_ = (size_t)((half)*128) * K + (size_t)(tile) * 64;           \
    gload16(Ags + ko_,                &Asm[(tile)&1][(half)*128 + wid*8][0]);     \
    gload16(Ags + ko_ + (size_t)64*K, &Asm[(tile)&1][(half)*128 + 64 + wid*8][0]); } }while(0)
#define STG_B(tile, r) do{ if ((tile) < NT){                                     \
    const size_t ko_ = (size_t)((r)*64) * K + (size_t)(tile) * 64;               \
    gload16(Bgs + ko_, &Bsm[(tile)&1][(r)*64 + wid*8][0]); } }while(0)

  STG_B(0,0); STG_B(0,1); STG_B(0,2);
  STG_A(0,0); STG_A(0,1);
  STG_B(1,0); STG_B(1,1); STG_B(1,2);
  asm volatile("s_waitcnt vmcnt(3)" ::: "memory");
  __builtin_amdgcn_sched_barrier(0);
  __builtin_amdgcn_s_barrier();

  bf16x8 fA[4][2], fB01[2][2], fB2[2];
  for (int u = 0; u < NU; ++u){
    const int t = 2 * u;
    // P0
#pragma unroll
    for (int mi = 0; mi < 4; ++mi){ fA[mi][0] = FRA(0, mi, 0); fA[mi][1] = FRA(0, mi, 1); }
#pragma unroll
    for (int ni = 0; ni < 2; ++ni){ fB01[ni][0] = FRB(0, ni, 0); fB01[ni][1] = FRB(0, ni, 1); }
    STG_A(t + 1, 0);
    asm volatile("s_waitcnt lgkmcnt(8)" ::: "memory");
    __builtin_amdgcn_s_barrier();
    asm volatile("s_waitcnt lgkmcnt(0)" ::: "memory");
    __builtin_amdgcn_sched_barrier(0);
    __builtin_amdgcn_s_setprio(1);
#pragma unroll
    for (int kh = 0; kh < 2; ++kh)
#pragma unroll
      for (int mi = 0; mi < 4; ++mi)
#pragma unroll
        for (int ni = 0; ni < 2; ++ni)
          acc[mi][ni] = mfma16(fA[mi][kh], fB01[ni][kh], acc[mi][ni]);
    __builtin_amdgcn_s_setprio(0);
    __builtin_amdgcn_s_barrier();
    // P1
    fB2[0] = FRB(0, 2, 0); fB2[1] = FRB(0, 2, 1);
    STG_A(t + 1, 1);
    __builtin_amdgcn_s_barrier();
    asm volatile("s_waitcnt lgkmcnt(0)" ::: "memory");
    __builtin_amdgcn_sched_barrier(0);
    __builtin_amdgcn_s_setprio(1);
#pragma unroll
    for (int kh = 0; kh < 2; ++kh)
#pragma unroll
      for (int mi = 0; mi < 4; ++mi)
        acc[mi][2] = mfma16(fA[mi][kh], fB2[kh], acc[mi][2]);
    __builtin_amdgcn_s_setprio(0);
    __builtin_amdgcn_s_barrier();
    // P2
#pragma unroll
    for (int mi = 0; mi < 4; ++mi){ fA[mi][0] = FRA(0, 4 + mi, 0); fA[mi][1] = FRA(0, 4 + mi, 1); }
    STG_B(t + 2, 0);
    __builtin_amdgcn_s_barrier();
    asm volatile("s_waitcnt lgkmcnt(0)" ::: "memory");
    __builtin_amdgcn_sched_barrier(0);
    __builtin_amdgcn_s_setprio(1);
#pragma unroll
    for (int kh = 0; kh < 2; ++kh)
#pragma unroll
      for (int mi = 0; mi < 4; ++mi)
#pragma unroll
        for (int ni = 0; ni < 2; ++ni)
          acc[4 + mi][ni] = mfma16(fA[mi][kh], fB01[ni][kh], acc[4 + mi][ni]);
    __builtin_amdgcn_s_setprio(0);
    __builtin_amdgcn_s_barrier();
    // P3
    STG_B(t + 2, 1); STG_B(t + 2, 2);
    __builtin_amdgcn_s_barrier();
    asm volatile("s_waitcnt lgkmcnt(0)" ::: "memory");
    __builtin_amdgcn_sched_barrier(0);
    __builtin_amdgcn_s_setprio(1);
#pragma unroll
    for (int kh = 0; kh < 2; ++kh)
#pragma unroll
      for (int mi = 0; mi < 4; ++mi)
        acc[4 + mi][2] = mfma16(fA[mi][kh], fB2[kh], acc[4 + mi][2]);
    __builtin_amdgcn_s_setprio(0);
    if (u == NU - 1) asm volatile("s_waitcnt vmcnt(0)" ::: "memory");
    else             asm volatile("s_waitcnt vmcnt(3)" ::: "memory");
    __builtin_amdgcn_sched_barrier(0);
    __builtin_amdgcn_s_barrier();
    // P4
#pragma unroll
    for (int mi = 0; mi < 4; ++mi){ fA[mi][0] = FRA(1, mi, 0); fA[mi][1] = FRA(1, mi, 1); }
#pragma unroll
    for (int ni = 0; ni < 2; ++ni){ fB01[ni][0] = FRB(1, ni, 0); fB01[ni][1] = FRB(1, ni, 1); }
    STG_A(t + 2, 0);
    asm volatile("s_waitcnt lgkmcnt(8)" ::: "memory");
    __builtin_amdgcn_s_barrier();
    asm volatile("s_waitcnt lgkmcnt(0)" ::: "memory");
    __builtin_amdgcn_sched_barrier(0);
    __builtin_amdgcn_s_setprio(1);
#pragma unroll
    for (int kh = 0; kh < 2; ++kh)
#pragma unroll
      for (int mi = 0; mi < 4; ++mi)
#pragma unroll
        for (int ni = 0; ni < 2; ++ni)
          acc[mi][ni] = mfma16(fA[mi][kh], fB01[ni][kh], acc[mi][ni]);
    __builtin_amdgcn_s_setprio(0);
    __builtin_amdgcn_s_barrier();
    // P5
    fB2[0] = FRB(1, 2, 0); fB2[1] = FRB(1, 2, 1);
    STG_A(t + 2, 1);
    __builtin_amdgcn_s_barrier();
    asm volatile("s_waitcnt lgkmcnt(0)" ::: "memory");
    __builtin_amdgcn_sched_barrier(0);
    __builtin_amdgcn_s_setprio(1);
#pragma unroll
    for (int kh = 0; kh < 2; ++kh)
#pragma unroll
      for (int mi = 0; mi < 4; ++mi)
        acc[mi][2] = mfma16(fA[mi][kh], fB2[kh], acc[mi][2]);
    __builtin_amdgcn_s_setprio(0);
    __builtin_amdgcn_s_barrier();
    // P6
#pragma unroll
    for (int mi = 0; mi < 4; ++mi){ fA[mi][0] = FRA(1, 4 + mi, 0); fA[mi][1] = FRA(1, 4 + mi, 1); }
    STG_B(t + 3, 0);
    __builtin_amdgcn_s_barrier();
    asm volatile("s_waitcnt lgkmcnt(0)" ::: "memory");
    __builtin_amdgcn_sched_barrier(0);
    __builtin_amdgcn_s_setprio(1);
#pragma unroll
    for (int kh = 0; kh < 2; ++kh)
#pragma unroll
      for (int mi = 0; mi < 4; ++mi)
#pragma unroll
        for (int ni = 0; ni < 2; ++ni)
          acc[4 + mi][ni] = mfma16(fA[mi][kh], fB01[ni][kh], acc[4 + mi][ni]);
    __builtin_amdgcn_s_setprio(0);
    __builtin_amdgcn_s_barrier();
    // P7
    STG_B(t + 3, 1); STG_B(t + 3, 2);
    __builtin_amdgcn_s_barrier();
    asm volatile("s_waitcnt lgkmcnt(0)" ::: "memory");
    __builtin_amdgcn_sched_barrier(0);
    __builtin_amdgcn_s_setprio(1);
#pragma unroll
    for (int kh = 0; kh < 2; ++kh)
#pragma unroll
      for (int mi = 0; mi < 4; ++mi)
        acc[4 + mi][2] = mfma16(fA[mi][kh], fB2[kh], acc[4 + mi][2]);
    __builtin_amdgcn_s_setprio(0);
    asm volatile("s_waitcnt vmcnt(3)" ::: "memory");
    __builtin_amdgcn_sched_barrier(0);
    __builtin_amdgcn_s_barrier();
  }
#undef FRA
#undef FRB
#undef STG_A
#undef STG_B

#pragma unroll
  for (int mi = 0; mi < 8; mi++)
#pragma unroll
    for (int ni = 0; ni < 3; ni++)
#pragma unroll
      for (int i = 0; i < 4; i++){
        size_t row = brow + wm*128 + mi*16 + lhi*4 + i;
        size_t col = bcol + wn*48 + ni*16 + l16;
        Cv[row * (size_t)N + col] = f2bf(acc[mi][ni][i]);
      }
}

// ---------------- GEMM2: 128x128 tile, 64 KB LDS, 2 blocks/CU, fp32 out (FROZEN) ----------------
__global__ __launch_bounds__(256) void k_gemm128(const u16* __restrict__ A, const u16* __restrict__ Bt,
                                                 float* __restrict__ Cv, int M, int N, int K){
  __shared__ __align__(16) u16 Asm[2][128][64];   // 32 KB
  __shared__ __align__(16) u16 Bsm[2][128][64];   // 32 KB
  const int tid = threadIdx.x, lane = tid & 63, wid = tid >> 6;   // 4 waves
  const int wm = wid >> 1, wn = wid & 1;
  const int l16 = lane & 15, lhi = lane >> 4;
  const int rx = l16 & 7;
  const int bid = blockIdx.x;
  const int xcd = bid & 7, jj = bid >> 3;          // 64 per XCD
  const size_t bcol = (size_t)(xcd * 4 + (jj & 3)) * 128;   // 32 bcols
  const size_t brow = (size_t)(jj >> 2) * 128;              // 16 brows

  const f32x4 vz = {0.f, 0.f, 0.f, 0.f};
  f32x4 acc[4][4];
#pragma unroll
  for (int m = 0; m < 4; m++)
#pragma unroll
    for (int n = 0; n < 4; n++) acc[m][n] = vz;

  const int srow = lane >> 3;                       // 0..7
  const int sg   = (lane & 7) ^ srow;               // pre-swizzled source granule
  const u16* Ags = A  + (brow + wid*8 + srow) * (size_t)K + sg*8;
  const u16* Bgs = Bt + (bcol + wid*8 + srow) * (size_t)K + sg*8;
  const int NT = K >> 6;

#define FRA2(buf, mi, kh) (*(const bf16x8*)&Asm[buf][wm*64 + (mi)*16 + l16][(((kh)*4 + lhi) ^ rx) << 3])
#define FRB2(buf, ni, kh) (*(const bf16x8*)&Bsm[buf][wn*64 + (ni)*16 + l16][(((kh)*4 + lhi) ^ rx) << 3])
#define STG2(tile) do{ if ((tile) < NT){                                          \
    const size_t ko_ = (size_t)(tile) * 64;                                       \
    _Pragma("unroll")                                                             \
    for (int r_ = 0; r_ < 4; ++r_){                                               \
      gload16(Ags + (size_t)(r_*32)*K + ko_, &Asm[(tile)&1][r_*32 + wid*8][0]);   \
      gload16(Bgs + (size_t)(r_*32)*K + ko_, &Bsm[(tile)&1][r_*32 + wid*8][0]);   \
    } } }while(0)

  STG2(0);
  asm volatile("s_waitcnt vmcnt(0)" ::: "memory");
  __builtin_amdgcn_sched_barrier(0);
  __builtin_amdgcn_s_barrier();

  bf16x8 fa[4], fb[4];
  for (int t = 0; t < NT; ++t){
    const int cur = t & 1;
    STG2(t + 1);
#pragma unroll
    for (int mi = 0; mi < 4; ++mi) fa[mi] = FRA2(cur, mi, 0);
#pragma unroll
    for (int ni = 0; ni < 4; ++ni) fb[ni] = FRB2(cur, ni, 0);
    __builtin_amdgcn_s_barrier();
    asm volatile("s_waitcnt lgkmcnt(0)" ::: "memory");
    __builtin_amdgcn_sched_barrier(0);
    __builtin_amdgcn_s_setprio(1);
#pragma unroll
    for (int mi = 0; mi < 4; ++mi)
#pragma unroll
      for (int ni = 0; ni < 4; ++ni)
        acc[mi][ni] = mfma16(fa[mi], fb[ni], acc[mi][ni]);
    __builtin_amdgcn_s_setprio(0);
    __builtin_amdgcn_s_barrier();
#pragma unroll
    for (int mi = 0; mi < 4; ++mi) fa[mi] = FRA2(cur, mi, 1);
#pragma unroll
    for (int ni = 0; ni < 4; ++ni) fb[ni] = FRB2(cur, ni, 1);
    __builtin_amdgcn_s_barrier();
    asm volatile("s_waitcnt lgkmcnt(0)" ::: "memory");
    __builtin_amdgcn_sched_barrier(0);
    __builtin_amdgcn_s_setprio(1);
#pragma unroll
    for (int mi = 0; mi < 4; ++mi)
#pragma unroll
      for (int ni = 0; ni < 4; ++ni)
        acc[mi][ni] = mfma16(fa[mi], fb[ni], acc[mi][ni]);
    __builtin_amdgcn_s_setprio(0);
    asm volatile("s_waitcnt vmcnt(0)" ::: "memory");
    __builtin_amdgcn_sched_barrier(0);
    __builtin_amdgcn_s_barrier();
  }
#undef FRA2
#undef FRB2
#undef STG2

#pragma unroll
  for (int mi = 0; mi < 4; mi++)
#pragma unroll
    for (int ni = 0; ni < 4; ni++)
#pragma unroll
      for (int i = 0; i < 4; i++){
        size_t row = brow + wm*64 + mi*16 + lhi*4 + i;
        size_t col = bcol + wn*64 + ni*16 + l16;
        Cv[row * (size_t)N + col] = acc[mi][ni][i];
      }
}

// ---------------- RMSNorm + RoPE ----------------
__global__ __launch_bounds__(256) void k_rmsrope(const u16* __restrict__ qkv, const float* __restrict__ cosp,
                                                 const float* __restrict__ sinp, const float* __restrict__ qw,
                                                 const float* __restrict__ kw, u16* __restrict__ Qr,
                                                 u16* __restrict__ Kr){
  int t = blockIdx.x;
  int lane = threadIdx.x & 63, w = threadIdx.x >> 6;
  int hh = blockIdx.y * 4 + w;
  bool isq = hh < NQH;
  int hl = isq ? hh : hh - NQH;
  const u16* src = qkv + (size_t)t * QKVN + (isq ? hl * HD : NQH * HD + hl * HD);
  unsigned u = *(const unsigned*)(src + 2 * lane);
  float x0 = bf2f((u16)(u & 0xffffu)), x1 = bf2f((u16)(u >> 16));
  float ss = x0 * x0 + x1 * x1;
#pragma unroll
  for (int m = 1; m < 64; m <<= 1) ss += __shfl_xor(ss, m);
  float rs = rsqrtf(ss * (1.f / HD) + 1e-6f);
  const float* wp = isq ? qw : kw;
  float w0 = wp[2 * lane], w1 = wp[2 * lane + 1];
  float xn0 = x0 * rs * w0, xn1 = x1 * rs * w1;
  float p0 = __shfl_xor(xn0, 32), p1 = __shfl_xor(xn1, 32);
  int j0 = (2 * lane) & 63;
  float c0 = cosp[t * 64 + j0], c1 = cosp[t * 64 + j0 + 1];
  float s0 = sinp[t * 64 + j0], s1 = sinp[t * 64 + j0 + 1];
  float o0, o1;
  if (lane < 32){ o0 = xn0 * c0 - p0 * s0; o1 = xn1 * c1 - p1 * s1; }
  else          { o0 = xn0 * c0 + p0 * s0; o1 = xn1 * c1 + p1 * s1; }
  if (isq){ o0 *= 0.08838834764831845f; o1 *= 0.08838834764831845f; }
  u16* dst = isq ? (Qr + ((size_t)hl * SEQ + t) * HD) : (Kr + ((size_t)hl * SEQ + t) * HD);
  *(unsigned*)(dst + 2 * lane) = (unsigned)f2bf(o0) | ((unsigned)f2bf(o1) << 16);
}

// ---------------- V slice -> VT[h][d][t] ----------------
__global__ void k_vt(const u16* __restrict__ qkv, u16* __restrict__ VT){
  __shared__ u16 t[32][33];
  int t0 = blockIdx.x * 32, d0 = blockIdx.y * 32, hv = blockIdx.z;
  int tx = threadIdx.x, ty = threadIdx.y;
#pragma unroll
  for (int i = 0; i < 32; i += 8)
    t[ty + i][tx] = qkv[(size_t)(t0 + ty + i) * QKVN + (NQH + NKVH) * HD + hv * HD + d0 + tx];
  __syncthreads();
#pragma unroll
  for (int i = 0; i < 32; i += 8)
    VT[((size_t)hv * HD + d0 + ty + i) * SEQ + t0 + tx] = t[tx][ty + i];
}

// ---------------- causal GQA flash attention, KVBLK=128 counted-wait pipeline ----------------
// r11 structure EXACTLY (measured best ~80 us; r13/r16 double-tile variants both
// regressed via the same P->Psm serialization mechanism -> family refuted, FROZEN).
__global__ __launch_bounds__(512) void k_attn(const u16* __restrict__ Q, const u16* __restrict__ Kg,
                                              const u16* __restrict__ VTg, u16* __restrict__ AO){
  __shared__ __align__(16) u16 Ksm[2][128][128];  // 64 KB, granule-swizzled (key row&7)
  __shared__ __align__(16) u16 Vsm[128][128];     // 32 KB [d][kv], swizzled (key d&7)
  __shared__ __align__(16) u16 Psm[8][16][136];   // 34.8 KB per-wave P [q][kv]
  int tid = threadIdx.x, lane = tid & 63, wid = tid >> 6;
  int l16 = lane & 15, lhi = lane >> 4;
  int bid = blockIdx.x;
  int kvg = bid & 7, rr = bid >> 3;               // 64 blocks per kv-group
  int J = 15 - (rr >> 2);                         // longest-first
  int hq = kvg * 4 + (rr & 3);
  int qb = J * 128;
  const u16* Kh = Kg  + (size_t)kvg * SEQ * HD;
  const u16* Vh = VTg + (size_t)kvg * HD * SEQ;
  const u16* Qh = Q   + (size_t)hq * SEQ * HD;

  bf16x8 qf[4];
#pragma unroll
  for (int ks = 0; ks < 4; ks++)
    qf[ks] = *(const bf16x8*)(Qh + (size_t)(qb + wid*16 + l16) * HD + ks*32 + lhi*8);

  const f32x4 vz = {0.f, 0.f, 0.f, 0.f};
  f32x4 o[8];
  float mrow[4], lrow[4];
#pragma unroll
  for (int n = 0; n < 8; n++) o[n] = vz;
#pragma unroll
  for (int i = 0; i < 4; i++){ mrow[i] = -1e30f; lrow[i] = 0.f; }

  int rsub = lane >> 4, g = lane & 15;
  const u16 *Ks0, *Ks1, *Ks2, *Ks3, *Vs0, *Vs1, *Vs2, *Vs3;
  {
    int r0 = wid*16 + 0*4 + rsub, r1 = wid*16 + 1*4 + rsub;
    int r2 = wid*16 + 2*4 + rsub, r3 = wid*16 + 3*4 + rsub;
    Ks0 = Kh + (size_t)r0 * HD + ((g ^ (r0 & 7)) << 3);
    Ks1 = Kh + (size_t)r1 * HD + ((g ^ (r1 & 7)) << 3);
    Ks2 = Kh + (size_t)r2 * HD + ((g ^ (r2 & 7)) << 3);
    Ks3 = Kh + (size_t)r3 * HD + ((g ^ (r3 & 7)) << 3);
    Vs0 = Vh + (size_t)r0 * SEQ + ((g ^ (r0 & 7)) << 3);
    Vs1 = Vh + (size_t)r1 * SEQ + ((g ^ (r1 & 7)) << 3);
    Vs2 = Vh + (size_t)r2 * SEQ + ((g ^ (r2 & 7)) << 3);
    Vs3 = Vh + (size_t)r3 * SEQ + ((g ^ (r3 & 7)) << 3);
  }

  gload16(Ks0, &Ksm[0][wid*16 +  0][0]);
  gload16(Ks1, &Ksm[0][wid*16 +  4][0]);
  gload16(Ks2, &Ksm[0][wid*16 +  8][0]);
  gload16(Ks3, &Ksm[0][wid*16 + 12][0]);
  asm volatile("s_waitcnt vmcnt(0)" ::: "memory");
  __builtin_amdgcn_sched_barrier(0);
  __builtin_amdgcn_s_barrier();

  int ntr = J + 1;
  int wrow0 = qb + wid*16;
  for (int t = 0; t < ntr; t++){
    int cur = t & 1, nxt = cur ^ 1;
    int kt0 = t << 7;
    bool pf = (t + 1 < ntr);
    gload16(Vs0 + kt0, &Vsm[wid*16 +  0][0]);
    gload16(Vs1 + kt0, &Vsm[wid*16 +  4][0]);
    gload16(Vs2 + kt0, &Vsm[wid*16 +  8][0]);
    gload16(Vs3 + kt0, &Vsm[wid*16 + 12][0]);
    if (pf){
      size_t ko = (size_t)(kt0 + 128) * HD;
      gload16(Ks0 + ko, &Ksm[nxt][wid*16 +  0][0]);
      gload16(Ks1 + ko, &Ksm[nxt][wid*16 +  4][0]);
      gload16(Ks2 + ko, &Ksm[nxt][wid*16 +  8][0]);
      gload16(Ks3 + ko, &Ksm[nxt][wid*16 + 12][0]);
    }
    f32x4 s[8];
#pragma unroll
    for (int n = 0; n < 8; n++) s[n] = vz;
    const u16* kbase = &Ksm[cur][0][0];
    __builtin_amdgcn_s_setprio(1);
#pragma unroll
    for (int n = 0; n < 8; n++){
      int row = n*16 + l16, rxk = row & 7;
#pragma unroll
      for (int ks = 0; ks < 4; ks++){
        bf16x8 kf = *(const bf16x8*)(kbase + row*128 + (((ks*4 + lhi) ^ rxk) << 3));
        s[n] = mfma16(qf[ks], kf, s[n]);
      }
    }
    __builtin_amdgcn_s_setprio(0);
    if (kt0 + 127 > wrow0){
#pragma unroll
      for (int n = 0; n < 8; n++)
#pragma unroll
        for (int i = 0; i < 4; i++)
          if (kt0 + n*16 + l16 > wrow0 + lhi*4 + i) s[n][i] = -1e30f;
    }
#pragma unroll
    for (int i = 0; i < 4; i++){
      float tm = fmaxf(fmaxf(fmaxf(s[0][i], s[1][i]), fmaxf(s[2][i], s[3][i])),
                       fmaxf(fmaxf(s[4][i], s[5][i]), fmaxf(s[6][i], s[7][i])));
      tm = fmaxf(tm, __shfl_xor(tm, 1));
      tm = fmaxf(tm, __shfl_xor(tm, 2));
      tm = fmaxf(tm, __shfl_xor(tm, 4));
      tm = fmaxf(tm, __shfl_xor(tm, 8));
      float nm = fmaxf(mrow[i], tm);
      float sc = __expf(mrow[i] - nm);
      mrow[i] = nm;
      float rsum = 0.f;
#pragma unroll
      for (int n = 0; n < 8; n++){
        float p = __expf(s[n][i] - nm);
        s[n][i] = p;
        rsum += p;
      }
      rsum += __shfl_xor(rsum, 1);
      rsum += __shfl_xor(rsum, 2);
      rsum += __shfl_xor(rsum, 4);
      rsum += __shfl_xor(rsum, 8);
      lrow[i] = lrow[i] * sc + rsum;
#pragma unroll
      for (int n = 0; n < 8; n++) o[n][i] *= sc;
    }
#pragma unroll
    for (int n = 0; n < 8; n++)
#pragma unroll
      for (int i = 0; i < 4; i++)
        Psm[wid][lhi*4 + i][n*16 + l16] = f2bf(s[n][i]);
    if (pf) asm volatile("s_waitcnt vmcnt(4)" ::: "memory");
    else    asm volatile("s_waitcnt vmcnt(0)" ::: "memory");
    __builtin_amdgcn_sched_barrier(0);
    __builtin_amdgcn_s_barrier();
    __builtin_amdgcn_sched_barrier(0);
    __builtin_amdgcn_s_setprio(1);
#pragma unroll
    for (int ksv = 0; ksv < 4; ksv++){
      bf16x8 pa = *(const bf16x8*)&Psm[wid][l16][ksv*32 + lhi*8];
#pragma unroll
      for (int n = 0; n < 8; n++){
        int row = n*16 + l16;
        bf16x8 vb = *(const bf16x8*)(&Vsm[0][0] + row*128 + (((ksv*4 + lhi) ^ (row & 7)) << 3));
        o[n] = mfma16(pa, vb, o[n]);
      }
    }
    __builtin_amdgcn_s_setprio(0);
    asm volatile("s_waitcnt vmcnt(0)" ::: "memory");
    __builtin_amdgcn_sched_barrier(0);
    __builtin_amdgcn_s_barrier();
  }
  float inv[4];
#pragma unroll
  for (int i = 0; i < 4; i++) inv[i] = 1.f / lrow[i];
#pragma unroll
  for (int n = 0; n < 8; n++)
#pragma unroll
    for (int i = 0; i < 4; i++){
      int trow = wrow0 + lhi*4 + i;
      AO[(size_t)trow * HID + hq * HD + n*16 + l16] = f2bf(o[n][i] * inv[i]);
    }
}

// ---------------- launch ----------------
extern "C" void kernel_launch(void* const* d_in, const int* in_sizes, int n_in,
                              void* d_out, int out_size, void* d_ws, size_t ws_size,
                              hipStream_t stream){
  const float* hs   = (const float*)d_in[0];
  const float* cosp = (const float*)d_in[1];
  const float* sinp = (const float*)d_in[2];
  const float* wqkv = (const float*)d_in[3];
  const float* wo   = (const float*)d_in[4];
  const float* qw   = (const float*)d_in[5];
  const float* kw   = (const float*)d_in[6];
  float* out = (float*)d_out;
  char* ws = (char*)d_ws;
  u16* XB    = (u16*)(ws + 0);            // 16.8 MB  X bf16 [2048][4096]
  u16* WQKVT = (u16*)(ws + 16777216);     // 50.3 MB  WqkvT bf16 [6144][4096]
  u16* WOT   = (u16*)(ws + 0);            // 33.6 MB  WoT bf16 [4096][4096] (after GEMM1)
  u16* QKV   = (u16*)(ws + 67108864);     // 25.2 MB  qkv bf16 [2048][6144]
  u16* QR    = (u16*)(ws + 92274688);     // 16.8 MB  Q bf16 [32][2048][128]
  u16* KR    = (u16*)(ws + 109051904);    //  4.2 MB  K bf16 [8][2048][128]
  u16* VTB   = (u16*)(ws + 113246208);    //  4.2 MB  VT bf16 [8][128][2048]
  u16* AOB   = (u16*)(ws + 117440512);    // 16.8 MB  attn out bf16 [2048][4096]

  k_cvt<<<(SEQ * HID / 4 + 255) / 256, 256, 0, stream>>>(hs, XB, SEQ * HID / 4);
  k_transpose_cvt<<<dim3(QKVN / 32, HID / 32), dim3(32, 8), 0, stream>>>(wqkv, WQKVT, HID, QKVN);
  // GEMM1: BN=192 -> 256 blocks = 8 XCD x (4 bcol x 8 brow), full machine
  k_gemm192<<<256, 512, 0, stream>>>(XB, WQKVT, QKV, SEQ, QKVN, HID);
  k_transpose_cvt<<<dim3(HID / 32, HID / 32), dim3(32, 8), 0, stream>>>(wo, WOT, HID, HID);
  k_rmsrope<<<dim3(SEQ, 10), 256, 0, stream>>>(QKV, cosp, sinp, qw, kw, QR, KR);
  k_vt<<<dim3(SEQ / 32, HD / 32, NKVH), dim3(32, 8), 0, stream>>>(QKV, VTB);
  // attn: 512 blocks longest-first (greedy-optimal makespan), 1 q-tile per block
  k_attn<<<512, 512, 0, stream>>>(QR, KR, VTB, AOB);
  // GEMM2: 128^2 tile, 512 blocks = 2 blocks/CU, fp32 out direct
  k_gemm128<<<512, 256, 0, stream>>>(AOB, WOT, out, SEQ, HID, HID);
}